// Round 17
// baseline (1349.455 us; speedup 1.0000x reference)
//
#include <hip/hip_runtime.h>
#include <cstdio>
#include <math.h>

#define NB 16
#define NC 512
#define T0 64
#define NOSC 128
#define UPLEN 24576
#define NTOT 16384
#define NWIN 32
#define NFRAMES 1024
#define NCROP 4096
#define NCHUNK 192
#define CHT 128

#define TWO_PI_D 6.283185307179586
#define INV_2PI_D 0.15915494309189535
#define K_PHASE (6.283185307179586/11025.0)

typedef unsigned short u16;
typedef short bf16x8 __attribute__((ext_vector_type(8)));
typedef short short8 __attribute__((ext_vector_type(8)));
typedef float f32x4 __attribute__((ext_vector_type(4)));

static __device__ __forceinline__ float lrelu_f(float x){ return x > 0.f ? x : 0.2f*x; }

static __device__ __forceinline__ u16 bf16_rne(float x){
  unsigned u = __float_as_uint(x);
  unsigned r = (u + 0x7FFFu + ((u >> 16) & 1u)) >> 16;
  return (u16)r;
}
static __device__ __forceinline__ void bf16_split(float x, u16& h, u16& l){
  h = bf16_rne(x);
  float hf = __uint_as_float(((unsigned)h) << 16);
  l = bf16_rne(x - hf);
}

// ---------------- tables ----------------
__global__ void k_tables(float* __restrict__ centers, float* __restrict__ erbs){
  int o = threadIdx.x;
  if (o < NOSC){
    double lg0 = log10(20.0);
    double lg1 = log10(5492.5);
    double e = (o == NOSC-1) ? lg1 : (o*(lg1-lg0))/(double)(NOSC-1) + lg0;
    float c = (float)pow(10.0, e);
    centers[o] = c;
    erbs[o] = c*0.108f + 24.7f;
  }
}

// ---------------- upsample coordinate table: per-t (i0,i1) + frac weight ----------------
__global__ __launch_bounds__(256) void k_ttab(int* __restrict__ tti, float* __restrict__ ttw){
  int t = blockIdx.x*256 + threadIdx.x;
  if (t < UPLEN){
    double coord = (t + 0.5)*(1.0/384.0) - 0.5;
    double fl = floor(coord);
    int lo = (int)fl;
    float w = (float)(coord - fl);
    int i0 = lo < 0 ? 0 : (lo > 63 ? 63 : lo);
    int i1 = lo+1 < 0 ? 0 : (lo+1 > 63 ? 63 : lo+1);
    tti[t] = i0 | (i1 << 16);
    ttw[t] = w;
  }
}

// ---------------- pointwise conv + lrelu (f32 accumulate, 4 chains) ----------------
__global__ __launch_bounds__(256) void k_conv1(const float* __restrict__ in, const float* __restrict__ w,
                                               float* __restrict__ out, int Cin, int Cout){
  int b = blockIdx.x;
  int lane = threadIdx.x & 63;
  int wv = __builtin_amdgcn_readfirstlane(threadIdx.x >> 6);
  int co0 = blockIdx.y*16 + wv*4;
  const float* inb = in + (size_t)b*Cin*T0 + lane;
  float a[2][4] = {{0,0,0,0},{0,0,0,0}};
  for (int ci = 0; ci < Cin; ci += 8){
    float v[8];
    #pragma unroll
    for (int u = 0; u < 8; ++u) v[u] = inb[(size_t)(ci+u)*T0];
    #pragma unroll
    for (int u = 0; u < 8; ++u)
      #pragma unroll
      for (int j = 0; j < 4; ++j)
        a[u&1][j] += v[u] * w[(size_t)(co0+j)*Cin + ci+u];
  }
  #pragma unroll
  for (int j = 0; j < 4; ++j)
    out[((size_t)b*Cout + co0 + j)*T0 + lane] = lrelu_f(a[0][j] + a[1][j]);
}

// ---------------- k=3 conv + lrelu (f32 accumulate, shfl neighbors) ----------------
__global__ __launch_bounds__(256) void k_conv3(const float* __restrict__ in, const float* __restrict__ w,
                                               float* __restrict__ out){
  int b = blockIdx.x;
  int lane = threadIdx.x & 63;
  int wv = __builtin_amdgcn_readfirstlane(threadIdx.x >> 6);
  int co0 = blockIdx.y*16 + wv*4;
  const float* inb = in + (size_t)b*NC*T0 + lane;
  float a[2][4] = {{0,0,0,0},{0,0,0,0}};
  for (int ci = 0; ci < NC; ci += 8){
    float v[8];
    #pragma unroll
    for (int u = 0; u < 8; ++u) v[u] = inb[(size_t)(ci+u)*T0];
    #pragma unroll
    for (int u = 0; u < 8; ++u){
      float vm = __shfl_up(v[u], 1);
      float vp = __shfl_down(v[u], 1);
      if (lane == 0) vm = 0.f;
      if (lane == 63) vp = 0.f;
      #pragma unroll
      for (int j = 0; j < 4; ++j){
        const float* wp = w + ((size_t)(co0+j)*NC + ci+u)*3;
        a[u&1][j] += wp[0]*vm + wp[1]*v[u] + wp[2]*vp;
      }
    }
  }
  #pragma unroll
  for (int j = 0; j < 4; ++j)
    out[((size_t)b*NC + co0 + j)*T0 + lane] = lrelu_f(a[0][j] + a[1][j]);
}

// ---------------- freq head (f64 accumulate — phase-sensitive path) ----------------
__global__ __launch_bounds__(256) void k_freq(const float* __restrict__ h, const float* __restrict__ w,
                                              const float* __restrict__ centers, const float* __restrict__ erbs,
                                              float* __restrict__ l_buf, float* __restrict__ f_buf){
  int b = blockIdx.x;
  int lane = threadIdx.x & 63;
  int wv = __builtin_amdgcn_readfirstlane(threadIdx.x >> 6);
  int o0 = blockIdx.y*16 + wv*4;
  const float* hb = h + (size_t)b*NC*T0 + lane;
  double a[2][4] = {{0,0,0,0},{0,0,0,0}};
  for (int ci = 0; ci < NC; ci += 8){
    float v[8];
    #pragma unroll
    for (int u = 0; u < 8; ++u) v[u] = hb[(size_t)(ci+u)*T0];
    #pragma unroll
    for (int u = 0; u < 8; ++u)
      #pragma unroll
      for (int j = 0; j < 4; ++j)
        a[u&1][j] += (double)v[u] * (double)w[(size_t)(o0+j)*NC + ci+u];
  }
  #pragma unroll
  for (int j = 0; j < 4; ++j){
    double av = a[0][j] + a[1][j];
    int o = o0 + j;
    if (o < NOSC){
      l_buf[((size_t)b*NOSC + o)*T0 + lane] = (float)(av*av);
    } else {
      int oo = o - NOSC;
      double fv = (double)centers[oo] + tanh(av)*0.5*(double)erbs[oo];
      f_buf[((size_t)b*NOSC + oo)*T0 + lane] = (float)fv;
    }
  }
}

// ---------------- weight prep: collapse k7 -> 8 taps, split bf16 hi/lo, MFMA-blocked layout ----------------
__global__ __launch_bounds__(256) void k_prepw3(const float* __restrict__ w, u16* __restrict__ Wh, u16* __restrict__ Wl){
  int gid = blockIdx.x*256 + threadIdx.x;   // co(512) x cig(64)
  int co = gid >> 6;
  int ci0 = (gid & 63)*8;
  float tv[8][8];                            // [tap][j]
  #pragma unroll
  for (int j = 0; j < 8; ++j){
    const float* wp = w + ((size_t)co*NC + ci0 + j)*7;
    float w0=wp[0],w1=wp[1],w2=wp[2],w3=wp[3],w4=wp[4],w5=wp[5],w6=wp[6];
    tv[0][j]=w0;    tv[1][j]=w1+w2; tv[2][j]=w3+w4; tv[3][j]=w5+w6;
    tv[4][j]=w0+w1; tv[5][j]=w2+w3; tv[6][j]=w4+w5; tv[7][j]=w6;
  }
  int cot = co >> 4, r16 = co & 15, cik = ci0 >> 5, kg = (ci0 >> 3) & 3;
  #pragma unroll
  for (int tap = 0; tap < 8; ++tap){
    short8 h8, l8;
    #pragma unroll
    for (int j = 0; j < 8; ++j){ u16 h,l; bf16_split(tv[tap][j],h,l); h8[j]=(short)h; l8[j]=(short)l; }
    size_t o = (((size_t)tap*32 + cot)*16 + cik)*512 + r16*32 + kg*8;
    *(short8*)(Wh+o) = h8;
    *(short8*)(Wl+o) = l8;
  }
}

// ---------------- activation prep: fp32 [ci][t] -> blocked bf16 hi/lo, pads fused ----------------
__global__ __launch_bounds__(256) void k_prepb3(const float* __restrict__ in, u16* __restrict__ Bh,
                                                u16* __restrict__ Bl, int Tin){
  __shared__ float lds[32][65];
  int t0 = blockIdx.x*64, cik = blockIdx.y, b = blockIdx.z;
  int ci0 = cik*32;
  int tid = threadIdx.x;
  if (blockIdx.x == 0 && tid < 128){
    int rr = tid >> 5, ci = tid & 31;
    int row = (rr < 2) ? rr : Tin + rr;
    size_t o = (((size_t)b*16 + cik)*(Tin+4) + row)*32 + ci;
    Bh[o] = 0;
    if (Bl) Bl[o] = 0;
  }
  #pragma unroll
  for (int u = 0; u < 2; ++u){
    int v = tid + u*256;
    int ci = v >> 4, tc = (v & 15)*4;
    float4 x = *(const float4*)(in + ((size_t)b*NC + ci0 + ci)*Tin + t0 + tc);
    lds[ci][tc]=x.x; lds[ci][tc+1]=x.y; lds[ci][tc+2]=x.z; lds[ci][tc+3]=x.w;
  }
  __syncthreads();
  int r = tid >> 2, g = tid & 3;
  short8 h8, l8;
  #pragma unroll
  for (int j = 0; j < 8; ++j){
    u16 h,l; bf16_split(lds[g*8+j][r], h, l);
    h8[j]=(short)h; l8[j]=(short)l;
  }
  size_t o = (((size_t)b*16 + cik)*(Tin+4) + 2 + t0 + r)*32 + g*8;
  *(short8*)(Bh+o) = h8;
  if (Bl) *(short8*)(Bl+o) = l8;
}

// ---------------- fused K-split combine + bias + lrelu + B-prep for next layer ----------------
__global__ __launch_bounds__(256) void k_combprep(const float* __restrict__ pbuf, const float* __restrict__ bias,
                                                  u16* __restrict__ Bh, u16* __restrict__ Bl, int Tout, int KS){
  __shared__ float lds[32][65];
  int t0 = blockIdx.x*64, cik = blockIdx.y, b = blockIdx.z;
  int ci0 = cik*32;
  int tid = threadIdx.x;
  const size_t slab = (size_t)NB*NC*Tout;
  if (blockIdx.x == 0 && tid < 128){
    int rr = tid >> 5, ci = tid & 31;
    int row = (rr < 2) ? rr : Tout + rr;
    size_t o = (((size_t)b*16 + cik)*(Tout+4) + row)*32 + ci;
    Bh[o] = 0;
    if (Bl) Bl[o] = 0;
  }
  #pragma unroll
  for (int u = 0; u < 2; ++u){
    int v = tid + u*256;
    int ci = v >> 4, tc = (v & 15)*4;
    size_t base = ((size_t)b*NC + ci0 + ci)*Tout + t0 + tc;
    float4 s = make_float4(0.f, 0.f, 0.f, 0.f);
    for (int ks = 0; ks < KS; ++ks){
      float4 x = *(const float4*)(pbuf + (size_t)ks*slab + base);
      s.x += x.x; s.y += x.y; s.z += x.z; s.w += x.w;
    }
    float bv = bias[ci0 + ci];
    lds[ci][tc]   = lrelu_f(s.x + bv);
    lds[ci][tc+1] = lrelu_f(s.y + bv);
    lds[ci][tc+2] = lrelu_f(s.z + bv);
    lds[ci][tc+3] = lrelu_f(s.w + bv);
  }
  __syncthreads();
  int r = tid >> 2, g = tid & 3;
  short8 h8, l8;
  #pragma unroll
  for (int j = 0; j < 8; ++j){
    u16 h,l; bf16_split(lds[g*8+j][r], h, l);
    h8[j]=(short)h; l8[j]=(short)l;
  }
  size_t o = (((size_t)b*16 + cik)*(Tout+4) + 2 + t0 + r)*32 + g*8;
  *(short8*)(Bh+o) = h8;
  if (Bl) *(short8*)(Bl+o) = l8;
}

// ---------------- MFMA upsample-conv, dense blocked operands, wide t-tile ----------------
template<bool FINAL, bool USEBL>
__global__ __launch_bounds__(128, 2) void k_nlmfma7(const u16* __restrict__ Wh, const u16* __restrict__ Wl,
                                                    const u16* __restrict__ Bh, const u16* __restrict__ Bl,
                                                    const float* __restrict__ bias, float* __restrict__ outp,
                                                    int Tin, int KS, int tsh, int nper){
  const int lane = threadIdx.x & 63;
  const int wv = __builtin_amdgcn_readfirstlane(threadIdx.x >> 6);
  const int r16 = lane & 15, kg = lane >> 4;
  const int bid = blockIdx.x;
  const int co_t = (bid & 7) >> 1;
  const int idx = (bid & 1)*nper + (bid >> 3);
  const int Tt = 1 << tsh;
  const int t_t = idx & (Tt - 1);
  const int zb = idx >> tsh;
  const int b  = zb & (NB-1);
  const int ks = zb >> 4;
  const int coT0 = co_t*8 + wv*4;
  const int t_w  = t_t*64;
  const int cikBeg = (ks * (NC / KS)) >> 5;
  const int cikEnd = cikBeg + ((NC / KS) >> 5);

  f32x4 acc[2][4][4];
  f32x4 zz = {0.f, 0.f, 0.f, 0.f};
  #pragma unroll
  for (int p = 0; p < 2; ++p)
    #pragma unroll
    for (int c = 0; c < 4; ++c)
      #pragma unroll
      for (int f = 0; f < 4; ++f) acc[p][c][f] = zz;

  const int laneOff = r16*32 + kg*8;

  for (int cik = cikBeg; cik < cikEnd; ++cik){
    const size_t bBase = (((size_t)b*16 + cik)*(Tin+4) + t_w + r16)*32 + kg*8;
    #pragma unroll
    for (int s = 0; s < 5; ++s){
      bf16x8 bh[4], bl[4];
      #pragma unroll
      for (int f = 0; f < 4; ++f){
        bh[f] = *(const bf16x8*)(Bh + bBase + (size_t)(s + f*16)*32);
        if (USEBL) bl[f] = *(const bf16x8*)(Bl + bBase + (size_t)(s + f*16)*32);
      }
      #pragma unroll
      for (int e = 0; e < 2; ++e){
        if ((e == 0 && s < 4) || (e == 1 && s >= 1)){
          const int tap = (e == 0) ? s : (3 + s);
          bf16x8 ah[4], al[4];
          #pragma unroll
          for (int c = 0; c < 4; ++c){
            size_t ao = (((size_t)tap*32 + coT0 + c)*16 + cik)*512 + laneOff;
            ah[c] = *(const bf16x8*)(Wh + ao);
            al[c] = *(const bf16x8*)(Wl + ao);
          }
          #pragma unroll
          for (int c = 0; c < 4; ++c){
            #pragma unroll
            for (int f = 0; f < 4; ++f){
              f32x4 a = acc[e][c][f];
              a = __builtin_amdgcn_mfma_f32_16x16x32_bf16(ah[c], bh[f], a, 0, 0, 0);
              if (USEBL)
                a = __builtin_amdgcn_mfma_f32_16x16x32_bf16(ah[c], bl[f], a, 0, 0, 0);
              a = __builtin_amdgcn_mfma_f32_16x16x32_bf16(al[c], bh[f], a, 0, 0, 0);
              acc[e][c][f] = a;
            }
          }
        }
      }
    }
  }

  const int Tout = 2*Tin;
  const size_t slab = (size_t)NB*NC*Tout;
  const int co_w = co_t*128 + wv*64;
  #pragma unroll
  for (int c = 0; c < 4; ++c){
    #pragma unroll
    for (int r = 0; r < 4; ++r){
      int co = co_w + c*16 + kg*4 + r;
      #pragma unroll
      for (int f = 0; f < 4; ++f){
        int t = t_w + f*16 + r16;
        if (FINAL){
          float bv = bias[co];
          float2 v;
          v.x = lrelu_f(acc[0][c][f][r] + bv);
          v.y = lrelu_f(acc[1][c][f][r] + bv);
          *(float2*)(outp + ((size_t)b*NC + co)*Tout + 2*t) = v;
        } else {
          float2 v;
          v.x = acc[0][c][f][r];
          v.y = acc[1][c][f][r];
          *(float2*)(outp + (size_t)ks*slab + ((size_t)b*NC + co)*Tout + 2*t) = v;
        }
      }
    }
  }
}

// ---------------- noise-loudness output (from final y3 buffer) ----------------
__global__ __launch_bounds__(256) void k_nlout(const float* __restrict__ y3, const float* __restrict__ w,
                                               float* __restrict__ n_l){
  int b = blockIdx.y;
  int j = blockIdx.x*256 + threadIdx.x;
  float acc[17];
  #pragma unroll
  for (int k = 0; k < 17; ++k) acc[k] = 0.f;
  const float* yb = y3 + (size_t)b*NC*NFRAMES + j;
  for (int ci = 0; ci < NC; ++ci){
    float v = yb[(size_t)ci*NFRAMES];
    #pragma unroll
    for (int k = 0; k < 17; ++k) acc[k] += v * w[k*NC + ci];
  }
  #pragma unroll
  for (int k = 0; k < 17; ++k)
    n_l[((size_t)b*17 + k)*NFRAMES + j] = acc[k]*acc[k];
}

// ---------------- nlout partials: ci-split over blocks, L4 K-split combine inline ----------------
__global__ __launch_bounds__(256) void k_nlout3(const float* __restrict__ pbuf, const float* __restrict__ w,
                                                const float* __restrict__ bias, float* __restrict__ qbuf, int KS){
  int b = blockIdx.y;
  int cs = blockIdx.z;
  int j = blockIdx.x*256 + threadIdx.x;
  const size_t slab = (size_t)NB*NC*NFRAMES;
  const size_t slabQ = (size_t)NB*17*NFRAMES;
  float acc[17];
  #pragma unroll
  for (int k = 0; k < 17; ++k) acc[k] = 0.f;
  const float* pb = pbuf + (size_t)b*NC*NFRAMES + j;
  int ci0 = cs*64;
  for (int ci = ci0; ci < ci0 + 64; ++ci){
    float s = pb[(size_t)ci*NFRAMES];
    for (int ks = 1; ks < KS; ++ks) s += pb[(size_t)ks*slab + (size_t)ci*NFRAMES];
    float v = lrelu_f(s + bias[ci]);
    #pragma unroll
    for (int k = 0; k < 17; ++k) acc[k] += v * w[k*NC + ci];
  }
  #pragma unroll
  for (int k = 0; k < 17; ++k)
    qbuf[(size_t)cs*slabQ + ((size_t)b*17 + k)*NFRAMES + j] = acc[k];
}

// ---------------- reduce CS partials + square -> n_l ----------------
__global__ __launch_bounds__(256) void k_nlsq(const float* __restrict__ qbuf, float* __restrict__ n_l){
  size_t e = (size_t)blockIdx.x*256 + threadIdx.x;     // NB*17*NFRAMES
  const size_t slabQ = (size_t)NB*17*NFRAMES;
  float s = 0.f;
  #pragma unroll
  for (int cs = 0; cs < 8; ++cs) s += qbuf[(size_t)cs*slabQ + e];
  n_l[e] = s*s;
}

// ---------------- noise bank ----------------
__global__ __launch_bounds__(256) void k_noise(const float* __restrict__ noise, const float* __restrict__ n_l,
                                               float* __restrict__ frames){
  __shared__ float ctab[NWIN], stab[NWIN];
  int tid = threadIdx.x;
  if (tid < NWIN){
    double ang = (TWO_PI_D/NWIN)*tid;
    ctab[tid] = (float)cos(ang);
    stab[tid] = (float)sin(ang);
  }
  __syncthreads();
  int j = blockIdx.x*256 + tid;
  int b = blockIdx.y;
  const float* src = noise + ((size_t)b*NFRAMES + j)*NWIN;
  float nz[NWIN];
  #pragma unroll
  for (int n = 0; n < NWIN; ++n) nz[n] = src[n]*2.f - 1.f;
  float y[NWIN];
  #pragma unroll
  for (int n = 0; n < NWIN; ++n) y[n] = 0.f;
  const float* g = n_l + (size_t)b*17*NFRAMES + j;
  for (int k = 0; k < 17; ++k){
    float A = 0.f, Bv = 0.f;
    int m = 0;
    #pragma unroll
    for (int n = 0; n < NWIN; ++n){
      A  += nz[n]*ctab[m];
      Bv += nz[n]*stab[m];
      m = (m + k) & (NWIN-1);
    }
    float gk = g[(size_t)k*NFRAMES];
    float sc = (k == 0 || k == 16) ? 1.f : 2.f;
    float ga = sc*gk*A, gb = sc*gk*Bv;
    m = 0;
    #pragma unroll
    for (int n = 0; n < NWIN; ++n){
      y[n] += ga*ctab[m] + gb*stab[m];
      m = (m + k) & (NWIN-1);
    }
  }
  float* dst = frames + ((size_t)b*NFRAMES + j)*NWIN;
  #pragma unroll
  for (int n = 0; n < NWIN; ++n) dst[n] = y[n] * (1.f/NWIN);
}

// ---------------- oscillator phase: per-chunk sums (table-driven) ----------------
__global__ __launch_bounds__(256) void k_chunksum(const float* __restrict__ f_buf, const int* __restrict__ tti,
                                                  const float* __restrict__ ttw, double* __restrict__ cb){
  int idx = blockIdx.x*256 + threadIdx.x;
  int bo = idx & (NB*NOSC - 1);
  int c  = idx >> 11;
  const float* f = f_buf + (size_t)bo*T0;
  double s = 0.0;
  int t0 = c*CHT;
  for (int i = 0; i < CHT; ++i){
    int t = t0 + i;
    int ii = tti[t];
    float w = ttw[t];
    float f0 = f[ii & 0xFFFF], f1 = f[ii >> 16];
    float v = f0*(1.f - w) + f1*w;
    v = fminf(fmaxf(v, 20.f), 5512.5f);
    s += (double)v;
  }
  cb[(size_t)bo*NCHUNK + c] = s;
}

__global__ void k_scan(double* __restrict__ cb){
  int bo = blockIdx.x*64 + threadIdx.x;
  if (bo < NB*NOSC){
    double* p = cb + (size_t)bo*NCHUNK;
    double run = 0.0;
    for (int c = 0; c < NCHUNK; ++c){ double v = p[c]; p[c] = run; run += v; }
  }
}

// ---------------- oscillator bank + noise add (table-driven, CHT=128) ----------------
__global__ __launch_bounds__(128) void k_osc(const float* __restrict__ f_buf, const float* __restrict__ l_buf,
                                             const double* __restrict__ cb, const int* __restrict__ tti,
                                             const float* __restrict__ ttw, const float* __restrict__ frames,
                                             float* __restrict__ sig){
  int c = blockIdx.x;       // 0..NCHUNK-1
  int b = blockIdx.y;
  int o = threadIdx.x;      // 0..127
  __shared__ float tile[32*129];
  __shared__ float harm[CHT];
  __shared__ float red[32][4];
  const float* f = f_buf + ((size_t)b*NOSC + o)*T0;
  const float* l = l_buf + ((size_t)b*NOSC + o)*T0;
  double sum = cb[((size_t)b*NOSC + o)*NCHUNK + c];
  int tstart = c*CHT;
  for (int sub = 0; sub < 4; ++sub){
    for (int i = 0; i < 32; ++i){
      int t = tstart + sub*32 + i;
      int ii = tti[t];
      float w = ttw[t];
      int i0 = ii & 0xFFFF, i1 = ii >> 16;
      float fv = f[i0]*(1.f - w) + f[i1]*w;
      fv = fminf(fmaxf(fv, 20.f), 5512.5f);
      float lv = l[i0]*(1.f - w) + l[i1]*w;
      sum += (double)fv;
      double ph = sum * K_PHASE;
      double q = floor(ph * INV_2PI_D);
      float phw = (float)(ph - q*TWO_PI_D);
      tile[i*129 + o] = __sinf(phw) * lv;
    }
    __syncthreads();
    {
      int r = o & 31, qd = o >> 5;
      float s = 0.f;
      const float* tp = tile + r*129 + qd*32;
      #pragma unroll
      for (int j = 0; j < 32; ++j) s += tp[j];
      red[r][qd] = s;
    }
    __syncthreads();
    if (o < 32) harm[sub*32 + o] = (red[o][0] + red[o][1]) + (red[o][2] + red[o][3]);
    __syncthreads();
  }
  {
    int t = tstart + o;
    float v = harm[o];
    int tn = t - NCROP;
    if (tn >= 0 && tn < NTOT){
      int j1 = tn >> 4, n1 = tn & 15;
      float nv = frames[((size_t)b*NFRAMES + j1)*NWIN + n1];
      if (j1 > 0) nv += frames[((size_t)b*NFRAMES + j1 - 1)*NWIN + n1 + 16];
      v += nv;
    }
    sig[(size_t)b*UPLEN + t] = v;
  }
}

// ---------------- per-batch max |sig| ----------------
__global__ __launch_bounds__(256) void k_max(const float* __restrict__ sig, float* __restrict__ maxa){
  int b = blockIdx.x;
  float m = 0.f;
  for (int i = threadIdx.x; i < UPLEN; i += 256)
    m = fmaxf(m, fabsf(sig[(size_t)b*UPLEN + i]));
  #pragma unroll
  for (int off = 32; off > 0; off >>= 1)
    m = fmaxf(m, __shfl_xor(m, off, 64));
  __shared__ float sm[4];
  if ((threadIdx.x & 63) == 0) sm[threadIdx.x >> 6] = m;
  __syncthreads();
  if (threadIdx.x == 0)
    maxa[b] = fmaxf(fmaxf(sm[0], sm[1]), fmaxf(sm[2], sm[3]));
}

// ---------------- normalize + crop ----------------
__global__ __launch_bounds__(256) void k_final(const float* __restrict__ sig, const float* __restrict__ maxa,
                                               float* __restrict__ out){
  int b = blockIdx.y;
  int i = blockIdx.x*256 + threadIdx.x;
  out[(size_t)b*NTOT + i] = sig[(size_t)b*UPLEN + NCROP + i] / (maxa[b] + 1e-8f);
}

extern "C" void kernel_launch(void* const* d_in, const int* in_sizes, int n_in,
                              void* d_out, int out_size, void* d_ws, size_t ws_size,
                              hipStream_t stream)
{
  (void)in_sizes; (void)n_in;
  const float* x     = (const float*)d_in[0];
  const float* w0    = (const float*)d_in[1];
  const float* w1    = (const float*)d_in[2];
  const float* w2    = (const float*)d_in[3];
  const float* w3    = (const float*)d_in[4];
  const float* wf    = (const float*)d_in[5];
  const float* wnl[4] = {(const float*)d_in[6], (const float*)d_in[8], (const float*)d_in[10], (const float*)d_in[12]};
  const float* bnl[4] = {(const float*)d_in[7], (const float*)d_in[9], (const float*)d_in[11], (const float*)d_in[13]};
  const float* wno   = (const float*)d_in[14];
  const float* noise = (const float*)d_in[15];
  float* out = (float*)d_out;

  char* base = (char*)d_ws;
  size_t off = 0;
  auto carve = [&](size_t bytes) -> void* {
    void* r = base + off;
    off += (bytes + 255) & ~(size_t)255;
    return r;
  };
  double* cbase  = (double*)carve(sizeof(double)*(size_t)NB*NOSC*NCHUNK);
  float* h_a     = (float*)carve(4ull*NB*NC*T0);
  float* h_b     = (float*)carve(4ull*NB*NC*T0);
  float* l_buf   = (float*)carve(4ull*NB*NOSC*T0);
  float* f_buf   = (float*)carve(4ull*NB*NOSC*T0);
  float* Vbuf    = (float*)carve(4ull*NB*NC*512);    // fallback path intermediates
  float* Ubuf    = (float*)carve(4ull*NB*NC*1024);   // y3 (fallback nlout input)
  float* n_l     = (float*)carve(4ull*NB*17*NFRAMES);
  float* frames  = (float*)carve(4ull*NB*NFRAMES*NWIN);
  float* sig     = (float*)carve(4ull*NB*UPLEN);
  float* maxa    = (float*)carve(4ull*NB);
  float* centers = (float*)carve(4ull*NOSC);
  float* erbs    = (float*)carve(4ull*NOSC);
  int*   tti     = (int*)carve(4ull*UPLEN);
  float* ttw     = (float*)carve(4ull*UPLEN);
  float* Qbuf    = (float*)carve(4ull*8*NB*17*NFRAMES);  // 8.9 MB nlout partials
  u16* Wh        = (u16*)carve(2ull*8*NC*NC);        // 4.2 MB, blocked layout
  u16* Wl        = (u16*)carve(2ull*8*NC*NC);
  u16* Bh        = (u16*)carve(2ull*NB*(512+4)*NC);  // 8.5 MB, blocked layout
  if (off > ws_size){
    fprintf(stderr, "kernel_launch: workspace too small: need %zu bytes, have %zu\n", off, ws_size);
    return;
  }
  u16* Bl = nullptr;
  size_t blBytes = ((2ull*NB*(512+4)*NC) + 255) & ~(size_t)255;
  if (off + blBytes <= ws_size){
    Bl = (u16*)carve(2ull*NB*(512+4)*NC);
  } else {
    fprintf(stderr, "kernel_launch: B-lo buffer dropped (ws %zu), using single-bf16 activations\n", ws_size);
  }
  // Tiered K-split partial buffer (max need: KS*Tout rows = 2048 -> 67 MB; tier2 halves).
  float* Pbuf = nullptr;
  int ksL[4] = {1, 1, 1, 1};
  bool l4Fused = false;
  {
    size_t t1 = ((4ull*NB*NC*2048) + 255) & ~(size_t)255;   // 67 MB
    size_t t2 = ((4ull*NB*NC*1024) + 255) & ~(size_t)255;   // 33.5 MB
    if (off + t1 <= ws_size){
      Pbuf = (float*)carve(4ull*NB*NC*2048);
      ksL[0] = 16; ksL[1] = 8; ksL[2] = 4; ksL[3] = 2;      // all layers 1024 blocks
      l4Fused = true;                                       // L4 comb fused into nlout3
    } else if (off + t2 <= ws_size){
      Pbuf = (float*)carve(4ull*NB*NC*1024);
      ksL[0] = 8; ksL[1] = 4; ksL[2] = 2; ksL[3] = 1;
      fprintf(stderr, "kernel_launch: Pbuf tier2 (ws %zu)\n", ws_size);
    } else {
      fprintf(stderr, "kernel_launch: Pbuf dropped (ws %zu), K-split disabled\n", ws_size);
    }
  }
  if (out_size != NB*NTOT){
    fprintf(stderr, "kernel_launch: unexpected out_size %d (want %d)\n", out_size, NB*NTOT);
  }

  k_tables<<<1, 128, 0, stream>>>(centers, erbs);
  k_ttab<<<dim3(UPLEN/256), 256, 0, stream>>>(tti, ttw);

  // main conv stack (f32 accumulation; freq head stays f64)
  k_conv1<<<dim3(NB, 32), 256, 0, stream>>>(x, w0, h_a, 256, 512);
  k_conv3<<<dim3(NB, 32), 256, 0, stream>>>(h_a, w1, h_b);
  k_conv3<<<dim3(NB, 32), 256, 0, stream>>>(h_b, w2, h_a);
  k_conv3<<<dim3(NB, 32), 256, 0, stream>>>(h_a, w3, h_b);   // h = h_b

  // freq / loudness head
  k_freq<<<dim3(NB, 16), 256, 0, stream>>>(h_b, wf, centers, erbs, l_buf, f_buf);

  // ---- noise-loudness branch ----
  auto launch_mfma = [&](int Tin, int KS, float* dst, const float* bias, bool final_){
    int Tt = Tin/64; if (Tt < 1) Tt = 1;
    int tsh = __builtin_ctz(Tt);
    int nblk = 4 * Tt * NB * KS;
    int nper = (Tt * NB * KS) / 2;
    if (final_){
      if (Bl) k_nlmfma7<true, true ><<<dim3(nblk), 128, 0, stream>>>(Wh, Wl, Bh, Bl, bias, dst, Tin, KS, tsh, nper);
      else    k_nlmfma7<true, false><<<dim3(nblk), 128, 0, stream>>>(Wh, Wl, Bh, nullptr, bias, dst, Tin, KS, tsh, nper);
    } else {
      if (Bl) k_nlmfma7<false, true ><<<dim3(nblk), 128, 0, stream>>>(Wh, Wl, Bh, Bl, bias, dst, Tin, KS, tsh, nper);
      else    k_nlmfma7<false, false><<<dim3(nblk), 128, 0, stream>>>(Wh, Wl, Bh, nullptr, bias, dst, Tin, KS, tsh, nper);
    }
  };

  const int TinL[4] = {64, 128, 256, 512};
  if (Pbuf){
    // fused pipeline: prep(h_b) -> [mfma -> combprep]x3 -> mfma L4
    k_prepw3<<<dim3(128), 256, 0, stream>>>(wnl[0], Wh, Wl);
    k_prepb3<<<dim3(1, 16, NB), 256, 0, stream>>>(h_b, Bh, Bl, 64);
    for (int L = 0; L < 3; ++L){
      int Tin = TinL[L], Tout = 2*Tin;
      launch_mfma(Tin, ksL[L], Pbuf, nullptr, false);
      k_prepw3<<<dim3(128), 256, 0, stream>>>(wnl[L+1], Wh, Wl);
      k_combprep<<<dim3(Tout/64, 16, NB), 256, 0, stream>>>(Pbuf, bnl[L], Bh, Bl, Tout, ksL[L]);
    }
    if (l4Fused){
      launch_mfma(512, ksL[3], Pbuf, nullptr, false);                  // 1024 blocks, partials
      k_nlout3<<<dim3(4, NB, 8), 256, 0, stream>>>(Pbuf, wno, bnl[3], Qbuf, ksL[3]);
      k_nlsq<<<dim3((NB*17*NFRAMES)/256), 256, 0, stream>>>(Qbuf, n_l);
    } else {
      launch_mfma(512, 1, Ubuf, bnl[3], true);
      k_nlout<<<dim3(4, NB), 256, 0, stream>>>(Ubuf, wno, n_l);
    }
  } else {
    // fallback: per-layer FINAL + standalone prep
    const float* srcs[4] = {h_b, Vbuf, Ubuf, Vbuf};
    float* dsts[4] = {Vbuf, Ubuf, Vbuf, Ubuf};
    for (int L = 0; L < 4; ++L){
      int Tin = TinL[L];
      k_prepw3<<<dim3(128), 256, 0, stream>>>(wnl[L], Wh, Wl);
      k_prepb3<<<dim3(Tin/64, 16, NB), 256, 0, stream>>>(srcs[L], Bh, Bl, Tin);
      launch_mfma(Tin, 1, dsts[L], bnl[L], true);
    }
    k_nlout<<<dim3(4, NB), 256, 0, stream>>>(Ubuf, wno, n_l);
  }

  // noise bank
  k_noise<<<dim3(4, NB), 256, 0, stream>>>(noise, n_l, frames);

  // oscillator bank
  k_chunksum<<<dim3((NB*NOSC*NCHUNK)/256), 256, 0, stream>>>(f_buf, tti, ttw, cbase);
  k_scan<<<dim3(32), 64, 0, stream>>>(cbase);
  k_osc<<<dim3(NCHUNK, NB), 128, 0, stream>>>(f_buf, l_buf, cbase, tti, ttw, frames, sig);

  // normalize + crop
  k_max<<<dim3(NB), 256, 0, stream>>>(sig, maxa);
  k_final<<<dim3(NTOT/256, NB), 256, 0, stream>>>(sig, maxa, out);
}

// Round 19
// 888.205 us; speedup vs baseline: 1.5193x; 1.5193x over previous
//
#include <hip/hip_runtime.h>
#include <cstdio>
#include <math.h>

#define NB 16
#define NC 512
#define T0 64
#define NOSC 128
#define UPLEN 24576
#define NTOT 16384
#define NWIN 32
#define NFRAMES 1024
#define NCROP 4096
#define NCHUNK 96
#define CHT 256

#define TWO_PI_D 6.283185307179586
#define INV_2PI_D 0.15915494309189535
#define K_PHASE (6.283185307179586/11025.0)

typedef unsigned short u16;
typedef short bf16x8 __attribute__((ext_vector_type(8)));
typedef short short8 __attribute__((ext_vector_type(8)));
typedef float f32x4 __attribute__((ext_vector_type(4)));

static __device__ __forceinline__ float lrelu_f(float x){ return x > 0.f ? x : 0.2f*x; }

static __device__ __forceinline__ u16 bf16_rne(float x){
  unsigned u = __float_as_uint(x);
  unsigned r = (u + 0x7FFFu + ((u >> 16) & 1u)) >> 16;
  return (u16)r;
}
static __device__ __forceinline__ void bf16_split(float x, u16& h, u16& l){
  h = bf16_rne(x);
  float hf = __uint_as_float(((unsigned)h) << 16);
  l = bf16_rne(x - hf);
}

// ---------------- tables ----------------
__global__ void k_tables(float* __restrict__ centers, float* __restrict__ erbs){
  int o = threadIdx.x;
  if (o < NOSC){
    double lg0 = log10(20.0);
    double lg1 = log10(5492.5);
    double e = (o == NOSC-1) ? lg1 : (o*(lg1-lg0))/(double)(NOSC-1) + lg0;
    float c = (float)pow(10.0, e);
    centers[o] = c;
    erbs[o] = c*0.108f + 24.7f;
  }
}

// ---------------- upsample coordinate table: per-t (i0,i1) + frac weight ----------------
__global__ __launch_bounds__(256) void k_ttab(int* __restrict__ tti, float* __restrict__ ttw){
  int t = blockIdx.x*256 + threadIdx.x;
  if (t < UPLEN){
    double coord = (t + 0.5)*(1.0/384.0) - 0.5;
    double fl = floor(coord);
    int lo = (int)fl;
    float w = (float)(coord - fl);
    int i0 = lo < 0 ? 0 : (lo > 63 ? 63 : lo);
    int i1 = lo+1 < 0 ? 0 : (lo+1 > 63 ? 63 : lo+1);
    tti[t] = i0 | (i1 << 16);
    ttw[t] = w;
  }
}

// ---------------- pointwise conv + lrelu (f32 accumulate, 4 chains) ----------------
__global__ __launch_bounds__(256) void k_conv1(const float* __restrict__ in, const float* __restrict__ w,
                                               float* __restrict__ out, int Cin, int Cout){
  int b = blockIdx.x;
  int lane = threadIdx.x & 63;
  int wv = __builtin_amdgcn_readfirstlane(threadIdx.x >> 6);
  int co0 = blockIdx.y*16 + wv*4;
  const float* inb = in + (size_t)b*Cin*T0 + lane;
  float a[2][4] = {{0,0,0,0},{0,0,0,0}};
  for (int ci = 0; ci < Cin; ci += 8){
    float v[8];
    #pragma unroll
    for (int u = 0; u < 8; ++u) v[u] = inb[(size_t)(ci+u)*T0];
    #pragma unroll
    for (int u = 0; u < 8; ++u)
      #pragma unroll
      for (int j = 0; j < 4; ++j)
        a[u&1][j] += v[u] * w[(size_t)(co0+j)*Cin + ci+u];
  }
  #pragma unroll
  for (int j = 0; j < 4; ++j)
    out[((size_t)b*Cout + co0 + j)*T0 + lane] = lrelu_f(a[0][j] + a[1][j]);
}

// ---------------- k=3 conv + lrelu (f32 accumulate, shfl neighbors) ----------------
__global__ __launch_bounds__(256) void k_conv3(const float* __restrict__ in, const float* __restrict__ w,
                                               float* __restrict__ out){
  int b = blockIdx.x;
  int lane = threadIdx.x & 63;
  int wv = __builtin_amdgcn_readfirstlane(threadIdx.x >> 6);
  int co0 = blockIdx.y*16 + wv*4;
  const float* inb = in + (size_t)b*NC*T0 + lane;
  float a[2][4] = {{0,0,0,0},{0,0,0,0}};
  for (int ci = 0; ci < NC; ci += 8){
    float v[8];
    #pragma unroll
    for (int u = 0; u < 8; ++u) v[u] = inb[(size_t)(ci+u)*T0];
    #pragma unroll
    for (int u = 0; u < 8; ++u){
      float vm = __shfl_up(v[u], 1);
      float vp = __shfl_down(v[u], 1);
      if (lane == 0) vm = 0.f;
      if (lane == 63) vp = 0.f;
      #pragma unroll
      for (int j = 0; j < 4; ++j){
        const float* wp = w + ((size_t)(co0+j)*NC + ci+u)*3;
        a[u&1][j] += wp[0]*vm + wp[1]*v[u] + wp[2]*vp;
      }
    }
  }
  #pragma unroll
  for (int j = 0; j < 4; ++j)
    out[((size_t)b*NC + co0 + j)*T0 + lane] = lrelu_f(a[0][j] + a[1][j]);
}

// ---------------- freq head (f64 accumulate — phase-sensitive path) ----------------
__global__ __launch_bounds__(256) void k_freq(const float* __restrict__ h, const float* __restrict__ w,
                                              const float* __restrict__ centers, const float* __restrict__ erbs,
                                              float* __restrict__ l_buf, float* __restrict__ f_buf){
  int b = blockIdx.x;
  int lane = threadIdx.x & 63;
  int wv = __builtin_amdgcn_readfirstlane(threadIdx.x >> 6);
  int o0 = blockIdx.y*16 + wv*4;
  const float* hb = h + (size_t)b*NC*T0 + lane;
  double a[2][4] = {{0,0,0,0},{0,0,0,0}};
  for (int ci = 0; ci < NC; ci += 8){
    float v[8];
    #pragma unroll
    for (int u = 0; u < 8; ++u) v[u] = hb[(size_t)(ci+u)*T0];
    #pragma unroll
    for (int u = 0; u < 8; ++u)
      #pragma unroll
      for (int j = 0; j < 4; ++j)
        a[u&1][j] += (double)v[u] * (double)w[(size_t)(o0+j)*NC + ci+u];
  }
  #pragma unroll
  for (int j = 0; j < 4; ++j){
    double av = a[0][j] + a[1][j];
    int o = o0 + j;
    if (o < NOSC){
      l_buf[((size_t)b*NOSC + o)*T0 + lane] = (float)(av*av);
    } else {
      int oo = o - NOSC;
      double fv = (double)centers[oo] + tanh(av)*0.5*(double)erbs[oo];
      f_buf[((size_t)b*NOSC + oo)*T0 + lane] = (float)fv;
    }
  }
}

// ---------------- weight prep: collapse k7 -> 8 taps, split bf16 hi/lo, MFMA-blocked layout ----------------
__global__ __launch_bounds__(256) void k_prepw3(const float* __restrict__ w, u16* __restrict__ Wh, u16* __restrict__ Wl){
  int gid = blockIdx.x*256 + threadIdx.x;   // co(512) x cig(64)
  int co = gid >> 6;
  int ci0 = (gid & 63)*8;
  float tv[8][8];                            // [tap][j]
  #pragma unroll
  for (int j = 0; j < 8; ++j){
    const float* wp = w + ((size_t)co*NC + ci0 + j)*7;
    float w0=wp[0],w1=wp[1],w2=wp[2],w3=wp[3],w4=wp[4],w5=wp[5],w6=wp[6];
    tv[0][j]=w0;    tv[1][j]=w1+w2; tv[2][j]=w3+w4; tv[3][j]=w5+w6;
    tv[4][j]=w0+w1; tv[5][j]=w2+w3; tv[6][j]=w4+w5; tv[7][j]=w6;
  }
  int cot = co >> 4, r16 = co & 15, cik = ci0 >> 5, kg = (ci0 >> 3) & 3;
  #pragma unroll
  for (int tap = 0; tap < 8; ++tap){
    short8 h8, l8;
    #pragma unroll
    for (int j = 0; j < 8; ++j){ u16 h,l; bf16_split(tv[tap][j],h,l); h8[j]=(short)h; l8[j]=(short)l; }
    size_t o = (((size_t)tap*32 + cot)*16 + cik)*512 + r16*32 + kg*8;
    *(short8*)(Wh+o) = h8;
    *(short8*)(Wl+o) = l8;
  }
}

// ---------------- activation prep: fp32 [ci][t] -> blocked bf16 hi/lo, pads fused ----------------
__global__ __launch_bounds__(256) void k_prepb3(const float* __restrict__ in, u16* __restrict__ Bh,
                                                u16* __restrict__ Bl, int Tin){
  __shared__ float lds[32][65];
  int t0 = blockIdx.x*64, cik = blockIdx.y, b = blockIdx.z;
  int ci0 = cik*32;
  int tid = threadIdx.x;
  if (blockIdx.x == 0 && tid < 128){
    int rr = tid >> 5, ci = tid & 31;
    int row = (rr < 2) ? rr : Tin + rr;
    size_t o = (((size_t)b*16 + cik)*(Tin+4) + row)*32 + ci;
    Bh[o] = 0;
    if (Bl) Bl[o] = 0;
  }
  #pragma unroll
  for (int u = 0; u < 2; ++u){
    int v = tid + u*256;
    int ci = v >> 4, tc = (v & 15)*4;
    float4 x = *(const float4*)(in + ((size_t)b*NC + ci0 + ci)*Tin + t0 + tc);
    lds[ci][tc]=x.x; lds[ci][tc+1]=x.y; lds[ci][tc+2]=x.z; lds[ci][tc+3]=x.w;
  }
  __syncthreads();
  int r = tid >> 2, g = tid & 3;
  short8 h8, l8;
  #pragma unroll
  for (int j = 0; j < 8; ++j){
    u16 h,l; bf16_split(lds[g*8+j][r], h, l);
    h8[j]=(short)h; l8[j]=(short)l;
  }
  size_t o = (((size_t)b*16 + cik)*(Tin+4) + 2 + t0 + r)*32 + g*8;
  *(short8*)(Bh+o) = h8;
  if (Bl) *(short8*)(Bl+o) = l8;
}

// ---------------- fused K-split combine + bias + lrelu + B-prep for next layer ----------------
__global__ __launch_bounds__(256) void k_combprep(const float* __restrict__ pbuf, const float* __restrict__ bias,
                                                  u16* __restrict__ Bh, u16* __restrict__ Bl, int Tout, int KS){
  __shared__ float lds[32][65];
  int t0 = blockIdx.x*64, cik = blockIdx.y, b = blockIdx.z;
  int ci0 = cik*32;
  int tid = threadIdx.x;
  const size_t slab = (size_t)NB*NC*Tout;
  if (blockIdx.x == 0 && tid < 128){
    int rr = tid >> 5, ci = tid & 31;
    int row = (rr < 2) ? rr : Tout + rr;
    size_t o = (((size_t)b*16 + cik)*(Tout+4) + row)*32 + ci;
    Bh[o] = 0;
    if (Bl) Bl[o] = 0;
  }
  #pragma unroll
  for (int u = 0; u < 2; ++u){
    int v = tid + u*256;
    int ci = v >> 4, tc = (v & 15)*4;
    size_t base = ((size_t)b*NC + ci0 + ci)*Tout + t0 + tc;
    float4 s = make_float4(0.f, 0.f, 0.f, 0.f);
    for (int ks = 0; ks < KS; ++ks){
      float4 x = *(const float4*)(pbuf + (size_t)ks*slab + base);
      s.x += x.x; s.y += x.y; s.z += x.z; s.w += x.w;
    }
    float bv = bias[ci0 + ci];
    lds[ci][tc]   = lrelu_f(s.x + bv);
    lds[ci][tc+1] = lrelu_f(s.y + bv);
    lds[ci][tc+2] = lrelu_f(s.z + bv);
    lds[ci][tc+3] = lrelu_f(s.w + bv);
  }
  __syncthreads();
  int r = tid >> 2, g = tid & 3;
  short8 h8, l8;
  #pragma unroll
  for (int j = 0; j < 8; ++j){
    u16 h,l; bf16_split(lds[g*8+j][r], h, l);
    h8[j]=(short)h; l8[j]=(short)l;
  }
  size_t o = (((size_t)b*16 + cik)*(Tout+4) + 2 + t0 + r)*32 + g*8;
  *(short8*)(Bh+o) = h8;
  if (Bl) *(short8*)(Bl+o) = l8;
}

// ---------------- MFMA upsample-conv, dense blocked operands, wide t-tile ----------------
template<bool FINAL, bool USEBL>
__global__ __launch_bounds__(128, 2) void k_nlmfma7(const u16* __restrict__ Wh, const u16* __restrict__ Wl,
                                                    const u16* __restrict__ Bh, const u16* __restrict__ Bl,
                                                    const float* __restrict__ bias, float* __restrict__ outp,
                                                    int Tin, int KS, int tsh, int nper){
  const int lane = threadIdx.x & 63;
  const int wv = __builtin_amdgcn_readfirstlane(threadIdx.x >> 6);
  const int r16 = lane & 15, kg = lane >> 4;
  const int bid = blockIdx.x;
  const int co_t = (bid & 7) >> 1;
  const int idx = (bid & 1)*nper + (bid >> 3);
  const int Tt = 1 << tsh;
  const int t_t = idx & (Tt - 1);
  const int zb = idx >> tsh;
  const int b  = zb & (NB-1);
  const int ks = zb >> 4;
  const int coT0 = co_t*8 + wv*4;
  const int t_w  = t_t*64;
  const int cikBeg = (ks * (NC / KS)) >> 5;
  const int cikEnd = cikBeg + ((NC / KS) >> 5);

  f32x4 acc[2][4][4];
  f32x4 zz = {0.f, 0.f, 0.f, 0.f};
  #pragma unroll
  for (int p = 0; p < 2; ++p)
    #pragma unroll
    for (int c = 0; c < 4; ++c)
      #pragma unroll
      for (int f = 0; f < 4; ++f) acc[p][c][f] = zz;

  const int laneOff = r16*32 + kg*8;

  for (int cik = cikBeg; cik < cikEnd; ++cik){
    const size_t bBase = (((size_t)b*16 + cik)*(Tin+4) + t_w + r16)*32 + kg*8;
    #pragma unroll
    for (int s = 0; s < 5; ++s){
      bf16x8 bh[4], bl[4];
      #pragma unroll
      for (int f = 0; f < 4; ++f){
        bh[f] = *(const bf16x8*)(Bh + bBase + (size_t)(s + f*16)*32);
        if (USEBL) bl[f] = *(const bf16x8*)(Bl + bBase + (size_t)(s + f*16)*32);
      }
      #pragma unroll
      for (int e = 0; e < 2; ++e){
        if ((e == 0 && s < 4) || (e == 1 && s >= 1)){
          const int tap = (e == 0) ? s : (3 + s);
          bf16x8 ah[4], al[4];
          #pragma unroll
          for (int c = 0; c < 4; ++c){
            size_t ao = (((size_t)tap*32 + coT0 + c)*16 + cik)*512 + laneOff;
            ah[c] = *(const bf16x8*)(Wh + ao);
            al[c] = *(const bf16x8*)(Wl + ao);
          }
          #pragma unroll
          for (int c = 0; c < 4; ++c){
            #pragma unroll
            for (int f = 0; f < 4; ++f){
              f32x4 a = acc[e][c][f];
              a = __builtin_amdgcn_mfma_f32_16x16x32_bf16(ah[c], bh[f], a, 0, 0, 0);
              if (USEBL)
                a = __builtin_amdgcn_mfma_f32_16x16x32_bf16(ah[c], bl[f], a, 0, 0, 0);
              a = __builtin_amdgcn_mfma_f32_16x16x32_bf16(al[c], bh[f], a, 0, 0, 0);
              acc[e][c][f] = a;
            }
          }
        }
      }
    }
  }

  const int Tout = 2*Tin;
  const size_t slab = (size_t)NB*NC*Tout;
  const int co_w = co_t*128 + wv*64;
  #pragma unroll
  for (int c = 0; c < 4; ++c){
    #pragma unroll
    for (int r = 0; r < 4; ++r){
      int co = co_w + c*16 + kg*4 + r;
      #pragma unroll
      for (int f = 0; f < 4; ++f){
        int t = t_w + f*16 + r16;
        if (FINAL){
          float bv = bias[co];
          float2 v;
          v.x = lrelu_f(acc[0][c][f][r] + bv);
          v.y = lrelu_f(acc[1][c][f][r] + bv);
          *(float2*)(outp + ((size_t)b*NC + co)*Tout + 2*t) = v;
        } else {
          float2 v;
          v.x = acc[0][c][f][r];
          v.y = acc[1][c][f][r];
          *(float2*)(outp + (size_t)ks*slab + ((size_t)b*NC + co)*Tout + 2*t) = v;
        }
      }
    }
  }
}

// ---------------- noise-loudness output (from final y3 buffer) ----------------
__global__ __launch_bounds__(256) void k_nlout(const float* __restrict__ y3, const float* __restrict__ w,
                                               float* __restrict__ n_l){
  int b = blockIdx.y;
  int j = blockIdx.x*256 + threadIdx.x;
  float acc[17];
  #pragma unroll
  for (int k = 0; k < 17; ++k) acc[k] = 0.f;
  const float* yb = y3 + (size_t)b*NC*NFRAMES + j;
  for (int ci = 0; ci < NC; ++ci){
    float v = yb[(size_t)ci*NFRAMES];
    #pragma unroll
    for (int k = 0; k < 17; ++k) acc[k] += v * w[k*NC + ci];
  }
  #pragma unroll
  for (int k = 0; k < 17; ++k)
    n_l[((size_t)b*17 + k)*NFRAMES + j] = acc[k]*acc[k];
}

// ---------------- nlout partials: ci-split over blocks, L4 K-split combine inline ----------------
__global__ __launch_bounds__(256) void k_nlout3(const float* __restrict__ pbuf, const float* __restrict__ w,
                                                const float* __restrict__ bias, float* __restrict__ qbuf, int KS){
  int b = blockIdx.y;
  int cs = blockIdx.z;
  int j = blockIdx.x*256 + threadIdx.x;
  const size_t slab = (size_t)NB*NC*NFRAMES;
  const size_t slabQ = (size_t)NB*17*NFRAMES;
  float acc[17];
  #pragma unroll
  for (int k = 0; k < 17; ++k) acc[k] = 0.f;
  const float* pb = pbuf + (size_t)b*NC*NFRAMES + j;
  int ci0 = cs*64;
  for (int ci = ci0; ci < ci0 + 64; ++ci){
    float s = pb[(size_t)ci*NFRAMES];
    for (int ks = 1; ks < KS; ++ks) s += pb[(size_t)ks*slab + (size_t)ci*NFRAMES];
    float v = lrelu_f(s + bias[ci]);
    #pragma unroll
    for (int k = 0; k < 17; ++k) acc[k] += v * w[k*NC + ci];
  }
  #pragma unroll
  for (int k = 0; k < 17; ++k)
    qbuf[(size_t)cs*slabQ + ((size_t)b*17 + k)*NFRAMES + j] = acc[k];
}

// ---------------- reduce CS partials + square -> n_l ----------------
__global__ __launch_bounds__(256) void k_nlsq(const float* __restrict__ qbuf, float* __restrict__ n_l){
  size_t e = (size_t)blockIdx.x*256 + threadIdx.x;     // NB*17*NFRAMES
  const size_t slabQ = (size_t)NB*17*NFRAMES;
  float s = 0.f;
  #pragma unroll
  for (int cs = 0; cs < 8; ++cs) s += qbuf[(size_t)cs*slabQ + e];
  n_l[e] = s*s;
}

// ---------------- noise bank ----------------
__global__ __launch_bounds__(256) void k_noise(const float* __restrict__ noise, const float* __restrict__ n_l,
                                               float* __restrict__ frames){
  __shared__ float ctab[NWIN], stab[NWIN];
  int tid = threadIdx.x;
  if (tid < NWIN){
    double ang = (TWO_PI_D/NWIN)*tid;
    ctab[tid] = (float)cos(ang);
    stab[tid] = (float)sin(ang);
  }
  __syncthreads();
  int j = blockIdx.x*256 + tid;
  int b = blockIdx.y;
  const float* src = noise + ((size_t)b*NFRAMES + j)*NWIN;
  float nz[NWIN];
  #pragma unroll
  for (int n = 0; n < NWIN; ++n) nz[n] = src[n]*2.f - 1.f;
  float y[NWIN];
  #pragma unroll
  for (int n = 0; n < NWIN; ++n) y[n] = 0.f;
  const float* g = n_l + (size_t)b*17*NFRAMES + j;
  for (int k = 0; k < 17; ++k){
    float A = 0.f, Bv = 0.f;
    int m = 0;
    #pragma unroll
    for (int n = 0; n < NWIN; ++n){
      A  += nz[n]*ctab[m];
      Bv += nz[n]*stab[m];
      m = (m + k) & (NWIN-1);
    }
    float gk = g[(size_t)k*NFRAMES];
    float sc = (k == 0 || k == 16) ? 1.f : 2.f;
    float ga = sc*gk*A, gb = sc*gk*Bv;
    m = 0;
    #pragma unroll
    for (int n = 0; n < NWIN; ++n){
      y[n] += ga*ctab[m] + gb*stab[m];
      m = (m + k) & (NWIN-1);
    }
  }
  float* dst = frames + ((size_t)b*NFRAMES + j)*NWIN;
  #pragma unroll
  for (int n = 0; n < NWIN; ++n) dst[n] = y[n] * (1.f/NWIN);
}

// ---------------- oscillator phase: per-chunk sums (table + full-ii cached interp, f64 sum) ----------------
__global__ __launch_bounds__(256) void k_chunksum(const float* __restrict__ f_buf, const int* __restrict__ tti,
                                                  const float* __restrict__ ttw, double* __restrict__ cb){
  int idx = blockIdx.x*256 + threadIdx.x;
  int bo = idx & (NB*NOSC - 1);
  int c  = idx >> 11;
  const float* f = f_buf + (size_t)bo*T0;
  double s = 0.0;
  int t0 = c*CHT;
  int cached = -1; float f0 = 0.f, f1 = 0.f;
  for (int i = 0; i < CHT; ++i){
    int t = t0 + i;
    int ii = tti[t];
    float w = ttw[t];
    if (ii != cached){ cached = ii; f0 = f[ii & 0xFFFF]; f1 = f[ii >> 16]; }
    float v = f0*(1.f - w) + f1*w;
    v = fminf(fmaxf(v, 20.f), 5512.5f);
    s += (double)v;
  }
  cb[(size_t)bo*NCHUNK + c] = s;
}

__global__ void k_scan(double* __restrict__ cb){
  int bo = blockIdx.x*64 + threadIdx.x;
  if (bo < NB*NOSC){
    double* p = cb + (size_t)bo*NCHUNK;
    double run = 0.0;
    for (int c = 0; c < NCHUNK; ++c){ double v = p[c]; p[c] = run; run += v; }
  }
}

// ---------------- oscillator bank + noise add (table + full-ii cache, f64 phase) ----------------
__global__ __launch_bounds__(128) void k_osc(const float* __restrict__ f_buf, const float* __restrict__ l_buf,
                                             const double* __restrict__ cb, const int* __restrict__ tti,
                                             const float* __restrict__ ttw, const float* __restrict__ frames,
                                             float* __restrict__ sig){
  int c = blockIdx.x;
  int b = blockIdx.y;
  int o = threadIdx.x;
  __shared__ float tile[64*129];
  __shared__ float harm[256];
  __shared__ float red[128];
  const float* f = f_buf + ((size_t)b*NOSC + o)*T0;
  const float* l = l_buf + ((size_t)b*NOSC + o)*T0;
  double sum = cb[((size_t)b*NOSC + o)*NCHUNK + c];
  int tstart = c*CHT;
  int cached = -1; float f0 = 0.f, f1 = 0.f, l0 = 0.f, l1 = 0.f;
  for (int sub = 0; sub < 4; ++sub){
    for (int i = 0; i < 64; ++i){
      int t = tstart + sub*64 + i;
      int ii = tti[t];
      float w = ttw[t];
      if (ii != cached){
        cached = ii;
        int i0 = ii & 0xFFFF, i1 = ii >> 16;
        f0 = f[i0]; f1 = f[i1]; l0 = l[i0]; l1 = l[i1];
      }
      float fv = f0*(1.f - w) + f1*w;
      fv = fminf(fmaxf(fv, 20.f), 5512.5f);
      float lv = l0*(1.f - w) + l1*w;
      sum += (double)fv;
      double ph = sum * K_PHASE;
      double q = floor(ph * INV_2PI_D);
      float phw = (float)(ph - q*TWO_PI_D);
      tile[i*129 + o] = __sinf(phw) * lv;
    }
    __syncthreads();
    {
      int row = o & 63, half = o >> 6;
      float s = 0.f;
      const float* tp = tile + row*129 + half*64;
      for (int j = 0; j < 64; ++j) s += tp[j];
      red[row*2 + half] = s;
    }
    __syncthreads();
    if (o < 64) harm[sub*64 + o] = red[o*2] + red[o*2 + 1];
    __syncthreads();
  }
  for (int i = o; i < CHT; i += 128){
    int t = tstart + i;
    float v = harm[i];
    int tn = t - NCROP;
    if (tn >= 0 && tn < NTOT){
      int j1 = tn >> 4, n1 = tn & 15;
      float nv = frames[((size_t)b*NFRAMES + j1)*NWIN + n1];
      if (j1 > 0) nv += frames[((size_t)b*NFRAMES + j1 - 1)*NWIN + n1 + 16];
      v += nv;
    }
    sig[(size_t)b*UPLEN + t] = v;
  }
}

// ---------------- per-batch max |sig| ----------------
__global__ __launch_bounds__(256) void k_max(const float* __restrict__ sig, float* __restrict__ maxa){
  int b = blockIdx.x;
  float m = 0.f;
  for (int i = threadIdx.x; i < UPLEN; i += 256)
    m = fmaxf(m, fabsf(sig[(size_t)b*UPLEN + i]));
  #pragma unroll
  for (int off = 32; off > 0; off >>= 1)
    m = fmaxf(m, __shfl_xor(m, off, 64));
  __shared__ float sm[4];
  if ((threadIdx.x & 63) == 0) sm[threadIdx.x >> 6] = m;
  __syncthreads();
  if (threadIdx.x == 0)
    maxa[b] = fmaxf(fmaxf(sm[0], sm[1]), fmaxf(sm[2], sm[3]));
}

// ---------------- normalize + crop ----------------
__global__ __launch_bounds__(256) void k_final(const float* __restrict__ sig, const float* __restrict__ maxa,
                                               float* __restrict__ out){
  int b = blockIdx.y;
  int i = blockIdx.x*256 + threadIdx.x;
  out[(size_t)b*NTOT + i] = sig[(size_t)b*UPLEN + NCROP + i] / (maxa[b] + 1e-8f);
}

extern "C" void kernel_launch(void* const* d_in, const int* in_sizes, int n_in,
                              void* d_out, int out_size, void* d_ws, size_t ws_size,
                              hipStream_t stream)
{
  (void)in_sizes; (void)n_in;
  const float* x     = (const float*)d_in[0];
  const float* w0    = (const float*)d_in[1];
  const float* w1    = (const float*)d_in[2];
  const float* w2    = (const float*)d_in[3];
  const float* w3    = (const float*)d_in[4];
  const float* wf    = (const float*)d_in[5];
  const float* wnl[4] = {(const float*)d_in[6], (const float*)d_in[8], (const float*)d_in[10], (const float*)d_in[12]};
  const float* bnl[4] = {(const float*)d_in[7], (const float*)d_in[9], (const float*)d_in[11], (const float*)d_in[13]};
  const float* wno   = (const float*)d_in[14];
  const float* noise = (const float*)d_in[15];
  float* out = (float*)d_out;

  char* base = (char*)d_ws;
  size_t off = 0;
  auto carve = [&](size_t bytes) -> void* {
    void* r = base + off;
    off += (bytes + 255) & ~(size_t)255;
    return r;
  };
  double* cbase  = (double*)carve(sizeof(double)*(size_t)NB*NOSC*NCHUNK);
  float* h_a     = (float*)carve(4ull*NB*NC*T0);
  float* h_b     = (float*)carve(4ull*NB*NC*T0);
  float* l_buf   = (float*)carve(4ull*NB*NOSC*T0);
  float* f_buf   = (float*)carve(4ull*NB*NOSC*T0);
  float* Vbuf    = (float*)carve(4ull*NB*NC*512);    // fallback path intermediates
  float* Ubuf    = (float*)carve(4ull*NB*NC*1024);   // y3 (fallback nlout input)
  float* n_l     = (float*)carve(4ull*NB*17*NFRAMES);
  float* frames  = (float*)carve(4ull*NB*NFRAMES*NWIN);
  float* sig     = (float*)carve(4ull*NB*UPLEN);
  float* maxa    = (float*)carve(4ull*NB);
  float* centers = (float*)carve(4ull*NOSC);
  float* erbs    = (float*)carve(4ull*NOSC);
  int*   tti     = (int*)carve(4ull*UPLEN);
  float* ttw     = (float*)carve(4ull*UPLEN);
  float* Qbuf    = (float*)carve(4ull*8*NB*17*NFRAMES);  // 8.9 MB nlout partials
  u16* Wh        = (u16*)carve(2ull*8*NC*NC);        // 4.2 MB, blocked layout
  u16* Wl        = (u16*)carve(2ull*8*NC*NC);
  u16* Bh        = (u16*)carve(2ull*NB*(512+4)*NC);  // 8.5 MB, blocked layout
  if (off > ws_size){
    fprintf(stderr, "kernel_launch: workspace too small: need %zu bytes, have %zu\n", off, ws_size);
    return;
  }
  u16* Bl = nullptr;
  size_t blBytes = ((2ull*NB*(512+4)*NC) + 255) & ~(size_t)255;
  if (off + blBytes <= ws_size){
    Bl = (u16*)carve(2ull*NB*(512+4)*NC);
  } else {
    fprintf(stderr, "kernel_launch: B-lo buffer dropped (ws %zu), using single-bf16 activations\n", ws_size);
  }
  // Tiered K-split partial buffer (max need: KS*Tout rows = 2048 -> 67 MB; tier2 halves).
  float* Pbuf = nullptr;
  int ksL[4] = {1, 1, 1, 1};
  bool l4Fused = false;
  {
    size_t t1 = ((4ull*NB*NC*2048) + 255) & ~(size_t)255;   // 67 MB
    size_t t2 = ((4ull*NB*NC*1024) + 255) & ~(size_t)255;   // 33.5 MB
    if (off + t1 <= ws_size){
      Pbuf = (float*)carve(4ull*NB*NC*2048);
      ksL[0] = 16; ksL[1] = 8; ksL[2] = 4; ksL[3] = 2;      // all layers 1024 blocks
      l4Fused = true;                                       // L4 comb fused into nlout3
    } else if (off + t2 <= ws_size){
      Pbuf = (float*)carve(4ull*NB*NC*1024);
      ksL[0] = 8; ksL[1] = 4; ksL[2] = 2; ksL[3] = 1;
      fprintf(stderr, "kernel_launch: Pbuf tier2 (ws %zu)\n", ws_size);
    } else {
      fprintf(stderr, "kernel_launch: Pbuf dropped (ws %zu), K-split disabled\n", ws_size);
    }
  }
  if (out_size != NB*NTOT){
    fprintf(stderr, "kernel_launch: unexpected out_size %d (want %d)\n", out_size, NB*NTOT);
  }

  k_tables<<<1, 128, 0, stream>>>(centers, erbs);
  k_ttab<<<dim3(UPLEN/256), 256, 0, stream>>>(tti, ttw);

  // main conv stack (f32 accumulation; freq head stays f64)
  k_conv1<<<dim3(NB, 32), 256, 0, stream>>>(x, w0, h_a, 256, 512);
  k_conv3<<<dim3(NB, 32), 256, 0, stream>>>(h_a, w1, h_b);
  k_conv3<<<dim3(NB, 32), 256, 0, stream>>>(h_b, w2, h_a);
  k_conv3<<<dim3(NB, 32), 256, 0, stream>>>(h_a, w3, h_b);   // h = h_b

  // freq / loudness head
  k_freq<<<dim3(NB, 16), 256, 0, stream>>>(h_b, wf, centers, erbs, l_buf, f_buf);

  // ---- noise-loudness branch ----
  auto launch_mfma = [&](int Tin, int KS, float* dst, const float* bias, bool final_){
    int Tt = Tin/64; if (Tt < 1) Tt = 1;
    int tsh = __builtin_ctz(Tt);
    int nblk = 4 * Tt * NB * KS;
    int nper = (Tt * NB * KS) / 2;
    if (final_){
      if (Bl) k_nlmfma7<true, true ><<<dim3(nblk), 128, 0, stream>>>(Wh, Wl, Bh, Bl, bias, dst, Tin, KS, tsh, nper);
      else    k_nlmfma7<true, false><<<dim3(nblk), 128, 0, stream>>>(Wh, Wl, Bh, nullptr, bias, dst, Tin, KS, tsh, nper);
    } else {
      if (Bl) k_nlmfma7<false, true ><<<dim3(nblk), 128, 0, stream>>>(Wh, Wl, Bh, Bl, bias, dst, Tin, KS, tsh, nper);
      else    k_nlmfma7<false, false><<<dim3(nblk), 128, 0, stream>>>(Wh, Wl, Bh, nullptr, bias, dst, Tin, KS, tsh, nper);
    }
  };

  const int TinL[4] = {64, 128, 256, 512};
  if (Pbuf){
    // fused pipeline: prep(h_b) -> [mfma -> combprep]x3 -> mfma L4
    k_prepw3<<<dim3(128), 256, 0, stream>>>(wnl[0], Wh, Wl);
    k_prepb3<<<dim3(1, 16, NB), 256, 0, stream>>>(h_b, Bh, Bl, 64);
    for (int L = 0; L < 3; ++L){
      int Tin = TinL[L], Tout = 2*Tin;
      launch_mfma(Tin, ksL[L], Pbuf, nullptr, false);
      k_prepw3<<<dim3(128), 256, 0, stream>>>(wnl[L+1], Wh, Wl);
      k_combprep<<<dim3(Tout/64, 16, NB), 256, 0, stream>>>(Pbuf, bnl[L], Bh, Bl, Tout, ksL[L]);
    }
    if (l4Fused){
      launch_mfma(512, ksL[3], Pbuf, nullptr, false);                  // 1024 blocks, partials
      k_nlout3<<<dim3(4, NB, 8), 256, 0, stream>>>(Pbuf, wno, bnl[3], Qbuf, ksL[3]);
      k_nlsq<<<dim3((NB*17*NFRAMES)/256), 256, 0, stream>>>(Qbuf, n_l);
    } else {
      launch_mfma(512, 1, Ubuf, bnl[3], true);
      k_nlout<<<dim3(4, NB), 256, 0, stream>>>(Ubuf, wno, n_l);
    }
  } else {
    // fallback: per-layer FINAL + standalone prep
    const float* srcs[4] = {h_b, Vbuf, Ubuf, Vbuf};
    float* dsts[4] = {Vbuf, Ubuf, Vbuf, Ubuf};
    for (int L = 0; L < 4; ++L){
      int Tin = TinL[L];
      k_prepw3<<<dim3(128), 256, 0, stream>>>(wnl[L], Wh, Wl);
      k_prepb3<<<dim3(Tin/64, 16, NB), 256, 0, stream>>>(srcs[L], Bh, Bl, Tin);
      launch_mfma(Tin, 1, dsts[L], bnl[L], true);
    }
    k_nlout<<<dim3(4, NB), 256, 0, stream>>>(Ubuf, wno, n_l);
  }

  // noise bank
  k_noise<<<dim3(4, NB), 256, 0, stream>>>(noise, n_l, frames);

  // oscillator bank
  k_chunksum<<<dim3((NB*NOSC*NCHUNK)/256), 256, 0, stream>>>(f_buf, tti, ttw, cbase);
  k_scan<<<dim3(32), 64, 0, stream>>>(cbase);
  k_osc<<<dim3(NCHUNK, NB), 128, 0, stream>>>(f_buf, l_buf, cbase, tti, ttw, frames, sig);

  // normalize + crop
  k_max<<<dim3(NB), 256, 0, stream>>>(sig, maxa);
  k_final<<<dim3(NTOT/256, NB), 256, 0, stream>>>(sig, maxa, out);
}